// Round 1
// baseline (752.177 us; speedup 1.0000x reference)
//
#include <hip/hip_runtime.h>
#include <hip/hip_bf16.h>
#include <math.h>

#define BB 4096
#define SS 64
#define DD 256
#define NH 4
#define DH 64
#define MM 32
#define NLAB 262144
#define TLAB 20480
#define ISM 0.17677669529663687f  /* 1/sqrt(32) */

// -------- kernel 1: query = masked-mean gather, then SLAY features -> phiq.
// Also zero-inits Zvec (block 0) before k_zvec runs (stream-ordered).
__global__ __launch_bounds__(256) void k_query_phi(
    const int* __restrict__ idx, const float* __restrict__ mask,
    const float* __restrict__ emb, const float* __restrict__ omega,
    float* __restrict__ phiq, float* __restrict__ Zvec,
    float s0f, float s1f, float q0f, float q1f, float w0f, float w1f)
{
    const int b = blockIdx.x, t = threadIdx.x;
    const int h = t >> 6, r = (t >> 5) & 1, m = t & 31;
    if (b == 0) Zvec[t] = 0.0f;

    // omega fragment for this thread's output feature (h,r,m): 64 regs
    float omg[DH];
    const float* ob = omega + (r * NH + h) * (DH * MM) + m;
#pragma unroll
    for (int d = 0; d < DH; ++d) omg[d] = ob[d * MM];

    // masked-mean over history
    float acc = 0.0f, msum = 0.0f;
    const int*   ib = idx  + b * SS;
    const float* mb = mask + b * SS;
#pragma unroll 4
    for (int s = 0; s < SS; ++s) {
        int   id = ib[s];
        float mv = mb[s];
        acc  += emb[id * DD + t] * mv;
        msum += mv;
    }
    float q = acc / fmaxf(msum, 1e-9f);

    // per-head norm: wave w == head w (64 dims == 64 lanes)
    float ss = q * q;
#pragma unroll
    for (int off = 32; off >= 1; off >>= 1) ss += __shfl_xor(ss, off);
    float xn = q / fmaxf(sqrtf(ss), 1e-6f);

    __shared__ float lxn[DD];
    lxn[t] = xn;
    __syncthreads();

    float p = 0.0f;
    const float* xb = lxn + h * DH;   // wave-uniform address -> LDS broadcast
#pragma unroll
    for (int d = 0; d < DH; ++d) p = fmaf(xb[d], omg[d], p);

    const float sv = r ? s1f : s0f, qv = r ? q1f : q0f, wv = r ? w1f : w0f;
    float poly = p * p * ISM;
    float arg  = fminf(fmaxf(fmaf(p, qv, -sv), -10.0f), 10.0f);
    phiq[b * DD + t] = poly * __expf(arg) * ISM * wv;
}

// -------- kernel 2: Z_vec = sum over all labels of phi_W (never materialized)
__global__ __launch_bounds__(256) void k_zvec(
    const float* __restrict__ W, const float* __restrict__ omega,
    float* __restrict__ Zvec, int lab_per_block,
    float s0f, float s1f, float q0f, float q1f, float w0f, float w1f)
{
    const int t = threadIdx.x;
    const int h = t >> 6, r = (t >> 5) & 1, m = t & 31;

    float omg[DH];
    const float* ob = omega + (r * NH + h) * (DH * MM) + m;
#pragma unroll
    for (int d = 0; d < DH; ++d) omg[d] = ob[d * MM];

    const float sv = r ? s1f : s0f, qv = r ? q1f : q0f, wv = r ? w1f : w0f;

    __shared__ float lxn[DD];
    float accphi = 0.0f;
    const int l0 = blockIdx.x * lab_per_block;
    for (int i = 0; i < lab_per_block; ++i) {
        const int l = l0 + i;
        float x = W[l * DD + t];
        float ss = x * x;
#pragma unroll
        for (int off = 32; off >= 1; off >>= 1) ss += __shfl_xor(ss, off);
        float xn = x / fmaxf(sqrtf(ss), 1e-6f);
        lxn[t] = xn;
        __syncthreads();
        float p = 0.0f;
        const float* xb = lxn + h * DH;
#pragma unroll
        for (int d = 0; d < DH; ++d) p = fmaf(xb[d], omg[d], p);
        float poly = p * p * ISM;
        float arg  = fminf(fmaxf(fmaf(p, qv, -sv), -10.0f), 10.0f);
        accphi += poly * __expf(arg) * ISM * wv;
        __syncthreads();
    }
    atomicAdd(&Zvec[t], accphi);
}

// -------- kernel 3: log_Z[b] = log(phiq[b] . Zvec + 1e-6); zero d_out
__global__ __launch_bounds__(256) void k_logz(
    const float* __restrict__ phiq, const float* __restrict__ Zvec,
    float* __restrict__ logZ, float* __restrict__ out)
{
    const int t = threadIdx.x, w = t >> 6, lane = t & 63;
    if (blockIdx.x == 0 && t == 0) out[0] = 0.0f;
    const int row = blockIdx.x * 4 + w;
    const float4* p4 = (const float4*)(phiq + row * DD);
    const float4* z4 = (const float4*)Zvec;
    float4 a = p4[lane], z = z4[lane];
    float dot = a.x * z.x + a.y * z.y + a.z * z.z + a.w * z.w;
#pragma unroll
    for (int off = 32; off >= 1; off >>= 1) dot += __shfl_xor(dot, off);
    if (lane == 0) logZ[row] = logf(dot + 1e-6f);
}

// -------- kernel 4: ragged positive-label loss terms
__global__ __launch_bounds__(256) void k_loss(
    const int* __restrict__ flab, const int* __restrict__ sids,
    const float* __restrict__ W, const float* __restrict__ omega,
    const float* __restrict__ phiq, const float* __restrict__ logZ,
    float* __restrict__ out, int lab_per_block,
    float s0f, float s1f, float q0f, float q1f, float w0f, float w1f)
{
    const int t = threadIdx.x;
    const int h = t >> 6, r = (t >> 5) & 1, m = t & 31;
    const int wid = t >> 6, lane = t & 63;

    float omg[DH];
    const float* ob = omega + (r * NH + h) * (DH * MM) + m;
#pragma unroll
    for (int d = 0; d < DH; ++d) omg[d] = ob[d * MM];

    const float sv = r ? s1f : s0f, qv = r ? q1f : q0f, wv = r ? w1f : w0f;

    __shared__ float lxn[DD];
    __shared__ float wpart[4];
    float acc = 0.0f;
    const int i0 = blockIdx.x * lab_per_block;
    for (int i = 0; i < lab_per_block; ++i) {
        const int gi  = i0 + i;
        const int l   = flab[gi];
        const int sid = sids[gi];
        float x = W[l * DD + t];
        float ss = x * x;
#pragma unroll
        for (int off = 32; off >= 1; off >>= 1) ss += __shfl_xor(ss, off);
        float xn = x / fmaxf(sqrtf(ss), 1e-6f);
        lxn[t] = xn;
        __syncthreads();
        float p = 0.0f;
        const float* xb = lxn + h * DH;
#pragma unroll
        for (int d = 0; d < DH; ++d) p = fmaf(xb[d], omg[d], p);
        float poly = p * p * ISM;
        float arg  = fminf(fmaxf(fmaf(p, qv, -sv), -10.0f), 10.0f);
        float phi  = poly * __expf(arg) * ISM * wv;
        float prod = phi * phiq[sid * DD + t];
#pragma unroll
        for (int off = 32; off >= 1; off >>= 1) prod += __shfl_xor(prod, off);
        if (lane == 0) wpart[wid] = prod;
        __syncthreads();
        if (t == 0) {
            float num = wpart[0] + wpart[1] + wpart[2] + wpart[3] + 1e-6f;
            acc += logZ[sid] - logf(num);
        }
    }
    if (t == 0) atomicAdd(out, acc * (1.0f / (float)BB));
}

extern "C" void kernel_launch(void* const* d_in, const int* in_sizes, int n_in,
                              void* d_out, int out_size, void* d_ws, size_t ws_size,
                              hipStream_t stream) {
    const int*   indices = (const int*)  d_in[0];
    const float* mask    = (const float*)d_in[1];
    const int*   flab    = (const int*)  d_in[2];
    const int*   sids    = (const int*)  d_in[3];
    const float* emb     = (const float*)d_in[4];
    const float* W       = (const float*)d_in[5];
    const float* omega   = (const float*)d_in[6];
    float* out = (float*)d_out;

    float* ws   = (float*)d_ws;
    float* phiq = ws;                   // BB*DD
    float* Zvec = phiq + BB * DD;       // DD
    float* logZ = Zvec + DD;            // BB

    // Gauss-Laguerre R=2 constants (double precision on host)
    const double C  = 2.0 + 1e-6;
    const double s2 = sqrt(2.0);
    const double n0 = (2.0 - s2) / C, n1 = (2.0 + s2) / C;
    const double wt0 = ((2.0 + s2) / 4.0) / C, wt1 = ((2.0 - s2) / 4.0) / C;
    const float s0f = (float)n0,        s1f = (float)n1;
    const float q0f = (float)sqrt(2.0 * n0), q1f = (float)sqrt(2.0 * n1);
    const float w0f = (float)sqrt(wt0), w1f = (float)sqrt(wt1);

    k_query_phi<<<BB, 256, 0, stream>>>(indices, mask, emb, omega, phiq, Zvec,
                                        s0f, s1f, q0f, q1f, w0f, w1f);
    const int LPB = 128;  // 2048 blocks
    k_zvec<<<NLAB / LPB, 256, 0, stream>>>(W, omega, Zvec, LPB,
                                           s0f, s1f, q0f, q1f, w0f, w1f);
    k_logz<<<BB / 4, 256, 0, stream>>>(phiq, Zvec, logZ, out);
    const int LPB2 = 8;   // 2560 blocks
    k_loss<<<TLAB / LPB2, 256, 0, stream>>>(flab, sids, W, omega, phiq, logZ,
                                            out, LPB2,
                                            s0f, s1f, q0f, q1f, w0f, w1f);
}

// Round 2
// 510.780 us; speedup vs baseline: 1.4726x; 1.4726x over previous
//
#include <hip/hip_runtime.h>
#include <hip/hip_bf16.h>
#include <math.h>

#define BB 4096
#define SS 64
#define DD 256
#define NH 4
#define DH 64
#define MM 32
#define NLAB 262144
#define TLAB 20480
#define ISM 0.17677669529663687f  /* 1/sqrt(32) */

typedef __attribute__((ext_vector_type(8))) short short8;
typedef __attribute__((ext_vector_type(4))) float f32x4;

static __device__ __forceinline__ short f2bf(float f) {
    __hip_bfloat16 h = __float2bfloat16(f);
    return *reinterpret_cast<short*>(&h);
}

// -------- kernel 1: query = masked-mean gather, then SLAY features -> phiq.
// Also zero-inits Zvec (block 0) before k_zvec runs (stream-ordered).
__global__ __launch_bounds__(256) void k_query_phi(
    const int* __restrict__ idx, const float* __restrict__ mask,
    const float* __restrict__ emb, const float* __restrict__ omega,
    float* __restrict__ phiq, float* __restrict__ Zvec,
    float s0f, float s1f, float q0f, float q1f, float cw0, float cw1)
{
    const int b = blockIdx.x, t = threadIdx.x;
    const int h = t >> 6, r = (t >> 5) & 1, m = t & 31;
    if (b == 0) Zvec[t] = 0.0f;

    __shared__ int   lidx[SS];
    __shared__ float lmk[SS];
    if (t < SS) { lidx[t] = idx[b * SS + t]; lmk[t] = mask[b * SS + t]; }

    // omega fragment for this thread's output feature (h,r,m): 64 regs
    float omg[DH];
    const float* ob = omega + (size_t)((r * NH + h) * DH) * MM + m;
#pragma unroll
    for (int d = 0; d < DH; ++d) omg[d] = ob[d * MM];

    __syncthreads();

    // masked-mean over history (loads unrolled for ILP)
    float acc = 0.0f, msum = 0.0f;
#pragma unroll 8
    for (int s = 0; s < SS; ++s) {
        int   id = lidx[s];
        float mv = lmk[s];
        acc   = fmaf(emb[(size_t)id * DD + t], mv, acc);
        msum += mv;
    }
    float q = acc / fmaxf(msum, 1e-9f);

    // per-head norm: wave w == head w (64 dims == 64 lanes)
    float ss = q * q;
#pragma unroll
    for (int off = 32; off >= 1; off >>= 1) ss += __shfl_xor(ss, off);
    float xn = q / fmaxf(sqrtf(ss), 1e-6f);

    __shared__ float lxn[DD];
    lxn[t] = xn;
    __syncthreads();

    float p = 0.0f;
    const float* xb = lxn + h * DH;   // wave-uniform address -> LDS broadcast
#pragma unroll
    for (int d = 0; d < DH; ++d) p = fmaf(xb[d], omg[d], p);

    const float sv = r ? s1f : s0f, qv = r ? q1f : q0f, cw = r ? cw1 : cw0;
    float arg = fminf(fmaxf(fmaf(p, qv, -sv), -10.0f), 10.0f);
    phiq[b * DD + t] = p * p * __expf(arg) * cw;
}

// -------- kernel 2 (MFMA): Z_vec = sum over all labels of phi_W.
// proj computed as bf16 MFMA of raw W rows x omega; per-(label,head) norm
// folded in afterwards as a row scale. Wave w handles head w; labels tiled 16.
__global__ __launch_bounds__(256) void k_zvec(
    const float* __restrict__ W, const float* __restrict__ omega,
    float* __restrict__ Zvec, int lab_per_block,
    float s0f, float s1f, float q0f, float q1f, float cw0, float cw1)
{
    const int t = threadIdx.x;
    const int h    = t >> 6;       // wave == head
    const int lane = t & 63;
    const int l15  = lane & 15;    // A row / D col within tile
    const int kg   = lane >> 4;    // k-group

    // B fragments (omega, resident): col n = nt*16 + l15, k = kh*32 + kg*8 + e
    short8 bf[4][2];
#pragma unroll
    for (int nt = 0; nt < 4; ++nt) {
        const int r = nt >> 1;
        const int m = (nt & 1) * 16 + l15;
        const float* ob = omega + (size_t)((r * NH + h) * DH) * MM + m;
#pragma unroll
        for (int kh = 0; kh < 2; ++kh)
#pragma unroll
            for (int e = 0; e < 8; ++e) {
                int d = kh * 32 + kg * 8 + e;
                bf[nt][kh][e] = f2bf(ob[(size_t)d * MM]);
            }
    }

    float zp[4] = {0.0f, 0.0f, 0.0f, 0.0f};
    const int l0 = blockIdx.x * lab_per_block;

    for (int tile = 0; tile < lab_per_block; tile += 16) {
        // A: 16 labels x K=64 (this head's slice), raw fp32 -> bf16
        const float* wp = W + (size_t)(l0 + tile + l15) * DD + h * DH + kg * 8;
        float4 f0 = *(const float4*)(wp);
        float4 f1 = *(const float4*)(wp + 4);
        float4 f2 = *(const float4*)(wp + 32);
        float4 f3 = *(const float4*)(wp + 36);

        // per-(label,head) sum of squares: this lane covers 16 of the 64 dims,
        // the 4 lanes sharing l15 cover all 64 -> xor-reduce over bits 4,5
        float ss = f0.x*f0.x + f0.y*f0.y + f0.z*f0.z + f0.w*f0.w
                 + f1.x*f1.x + f1.y*f1.y + f1.z*f1.z + f1.w*f1.w
                 + f2.x*f2.x + f2.y*f2.y + f2.z*f2.z + f2.w*f2.w
                 + f3.x*f3.x + f3.y*f3.y + f3.z*f3.z + f3.w*f3.w;
        ss += __shfl_xor(ss, 16);
        ss += __shfl_xor(ss, 32);
        float rn = 1.0f / fmaxf(sqrtf(ss), 1e-6f);

        // redistribute: D row for (kg, reg rr) is kg*4+rr; lane j<16 holds row j
        float rnr[4];
#pragma unroll
        for (int rr = 0; rr < 4; ++rr) rnr[rr] = __shfl(rn, kg * 4 + rr);

        short8 a0, a1;
        a0[0]=f2bf(f0.x); a0[1]=f2bf(f0.y); a0[2]=f2bf(f0.z); a0[3]=f2bf(f0.w);
        a0[4]=f2bf(f1.x); a0[5]=f2bf(f1.y); a0[6]=f2bf(f1.z); a0[7]=f2bf(f1.w);
        a1[0]=f2bf(f2.x); a1[1]=f2bf(f2.y); a1[2]=f2bf(f2.z); a1[3]=f2bf(f2.w);
        a1[4]=f2bf(f3.x); a1[5]=f2bf(f3.y); a1[6]=f2bf(f3.z); a1[7]=f2bf(f3.w);

        f32x4 acc[4];
#pragma unroll
        for (int nt = 0; nt < 4; ++nt) {
            f32x4 c = {0.0f, 0.0f, 0.0f, 0.0f};
            c = __builtin_amdgcn_mfma_f32_16x16x32_bf16(a0, bf[nt][0], c, 0, 0, 0);
            c = __builtin_amdgcn_mfma_f32_16x16x32_bf16(a1, bf[nt][1], c, 0, 0, 0);
            acc[nt] = c;
        }

#pragma unroll
        for (int nt = 0; nt < 4; ++nt) {
            const float qv = (nt >> 1) ? q1f : q0f;
            const float sv = (nt >> 1) ? s1f : s0f;
            const float cw = (nt >> 1) ? cw1 : cw0;
            float zs = 0.0f;
#pragma unroll
            for (int rr = 0; rr < 4; ++rr) {
                float p   = acc[nt][rr] * rnr[rr];
                float arg = fminf(fmaxf(fmaf(p, qv, -sv), -10.0f), 10.0f);
                zs = fmaf(p * p * __expf(arg), cw, zs);
            }
            zp[nt] += zs;
        }
    }

    // column sums: reduce across the 4 row-groups (lanes sharing l15)
#pragma unroll
    for (int nt = 0; nt < 4; ++nt) {
        float z = zp[nt];
        z += __shfl_xor(z, 16);
        z += __shfl_xor(z, 32);
        if (lane < 16) atomicAdd(&Zvec[h * 64 + nt * 16 + lane], z);
    }
}

// -------- kernel 3: log_Z[b] = log(phiq[b] . Zvec + 1e-6); zero d_out
__global__ __launch_bounds__(256) void k_logz(
    const float* __restrict__ phiq, const float* __restrict__ Zvec,
    float* __restrict__ logZ, float* __restrict__ out)
{
    const int t = threadIdx.x, w = t >> 6, lane = t & 63;
    if (blockIdx.x == 0 && t == 0) out[0] = 0.0f;
    const int row = blockIdx.x * 4 + w;
    const float4* p4 = (const float4*)(phiq + (size_t)row * DD);
    const float4* z4 = (const float4*)Zvec;
    float4 a = p4[lane], z = z4[lane];
    float dot = a.x * z.x + a.y * z.y + a.z * z.z + a.w * z.w;
#pragma unroll
    for (int off = 32; off >= 1; off >>= 1) dot += __shfl_xor(dot, off);
    if (lane == 0) logZ[row] = logf(dot + 1e-6f);
}

// -------- kernel 4: ragged positive-label loss terms
__global__ __launch_bounds__(256) void k_loss(
    const int* __restrict__ flab, const int* __restrict__ sids,
    const float* __restrict__ W, const float* __restrict__ omega,
    const float* __restrict__ phiq, const float* __restrict__ logZ,
    float* __restrict__ out, int lab_per_block,
    float s0f, float s1f, float q0f, float q1f, float cw0, float cw1)
{
    const int t = threadIdx.x;
    const int h = t >> 6, r = (t >> 5) & 1, m = t & 31;
    const int wid = t >> 6, lane = t & 63;

    float omg[DH];
    const float* ob = omega + (size_t)((r * NH + h) * DH) * MM + m;
#pragma unroll
    for (int d = 0; d < DH; ++d) omg[d] = ob[d * MM];

    const float sv = r ? s1f : s0f, qv = r ? q1f : q0f, cw = r ? cw1 : cw0;

    __shared__ float lxn[DD];
    __shared__ float wpart[4];
    float acc = 0.0f;
    const int i0 = blockIdx.x * lab_per_block;
    for (int i = 0; i < lab_per_block; ++i) {
        const int gi  = i0 + i;
        const int l   = flab[gi];
        const int sid = sids[gi];
        float x = W[(size_t)l * DD + t];
        float ss = x * x;
#pragma unroll
        for (int off = 32; off >= 1; off >>= 1) ss += __shfl_xor(ss, off);
        float xn = x / fmaxf(sqrtf(ss), 1e-6f);
        lxn[t] = xn;
        __syncthreads();
        float p = 0.0f;
        const float* xb = lxn + h * DH;
#pragma unroll
        for (int d = 0; d < DH; ++d) p = fmaf(xb[d], omg[d], p);
        float arg = fminf(fmaxf(fmaf(p, qv, -sv), -10.0f), 10.0f);
        float phi = p * p * __expf(arg) * cw;
        float prod = phi * phiq[(size_t)sid * DD + t];
#pragma unroll
        for (int off = 32; off >= 1; off >>= 1) prod += __shfl_xor(prod, off);
        if (lane == 0) wpart[wid] = prod;
        __syncthreads();
        if (t == 0) {
            float num = wpart[0] + wpart[1] + wpart[2] + wpart[3] + 1e-6f;
            acc += logZ[sid] - logf(num);
        }
    }
    if (t == 0) atomicAdd(out, acc * (1.0f / (float)BB));
}

extern "C" void kernel_launch(void* const* d_in, const int* in_sizes, int n_in,
                              void* d_out, int out_size, void* d_ws, size_t ws_size,
                              hipStream_t stream) {
    const int*   indices = (const int*)  d_in[0];
    const float* mask    = (const float*)d_in[1];
    const int*   flab    = (const int*)  d_in[2];
    const int*   sids    = (const int*)  d_in[3];
    const float* emb     = (const float*)d_in[4];
    const float* W       = (const float*)d_in[5];
    const float* omega   = (const float*)d_in[6];
    float* out = (float*)d_out;

    float* ws   = (float*)d_ws;
    float* phiq = ws;                   // BB*DD
    float* Zvec = phiq + BB * DD;       // DD
    float* logZ = Zvec + DD;            // BB

    // Gauss-Laguerre R=2 constants (double precision on host)
    const double C  = 2.0 + 1e-6;
    const double s2 = sqrt(2.0);
    const double n0 = (2.0 - s2) / C, n1 = (2.0 + s2) / C;
    const double wt0 = ((2.0 + s2) / 4.0) / C, wt1 = ((2.0 - s2) / 4.0) / C;
    const float s0f = (float)n0,        s1f = (float)n1;
    const float q0f = (float)sqrt(2.0 * n0), q1f = (float)sqrt(2.0 * n1);
    const float cw0 = (float)(ISM * ISM * sqrt(wt0));
    const float cw1 = (float)(ISM * ISM * sqrt(wt1));

    k_query_phi<<<BB, 256, 0, stream>>>(indices, mask, emb, omega, phiq, Zvec,
                                        s0f, s1f, q0f, q1f, cw0, cw1);
    const int LPB = 256;  // 1024 blocks, 16 label-tiles per wave
    k_zvec<<<NLAB / LPB, 256, 0, stream>>>(W, omega, Zvec, LPB,
                                           s0f, s1f, q0f, q1f, cw0, cw1);
    k_logz<<<BB / 4, 256, 0, stream>>>(phiq, Zvec, logZ, out);
    const int LPB2 = 8;   // 2560 blocks
    k_loss<<<TLAB / LPB2, 256, 0, stream>>>(flab, sids, W, omega, phiq, logZ,
                                            out, LPB2,
                                            s0f, s1f, q0f, q1f, cw0, cw1);
}

// Round 6
// 483.765 us; speedup vs baseline: 1.5548x; 1.0558x over previous
//
#include <hip/hip_runtime.h>
#include <hip/hip_bf16.h>
#include <math.h>

#define BB 4096
#define SS 64
#define DD 256
#define NH 4
#define DH 64
#define MM 32
#define NLAB 262144
#define TLAB 20480
#define ISM 0.17677669529663687f  /* 1/sqrt(32) */

#define NZBLK 1024   /* k_phi blocks doing W labels: 256 labels each */
#define NQBLK 16     /* k_phi blocks doing queries: 256 samples each */

typedef __attribute__((ext_vector_type(8))) short short8;
typedef __attribute__((ext_vector_type(4))) float f32x4;

static __device__ __forceinline__ short f2bf(float f) {
    __hip_bfloat16 h = __float2bfloat16(f);
    return *reinterpret_cast<short*>(&h);
}

// -------- kernel 1: masked-mean gather -> normalized query (fp32).
// wave w = sample; lane covers 4 dims via float4. Also zeroes Zvec.
__global__ __launch_bounds__(256) void k_gather(
    const int* __restrict__ idx, const float* __restrict__ mask,
    const float* __restrict__ emb, float* __restrict__ xq,
    float* __restrict__ Zvec)
{
    const int t = threadIdx.x, w = t >> 6, lane = t & 63;
    const int b = blockIdx.x * 4 + w;
    if (blockIdx.x == 0) Zvec[t] = 0.0f;

    const int   id0 = idx [b * SS + lane];
    const float mk0 = mask[b * SS + lane];
    float msum = mk0;
#pragma unroll
    for (int off = 32; off >= 1; off >>= 1) msum += __shfl_xor(msum, off);

    const float* ebase = emb + (size_t)lane * 4;
    float4 acc = {0.f, 0.f, 0.f, 0.f};
#pragma unroll 8
    for (int s = 0; s < SS; ++s) {
        const int   ids = __shfl(id0, s);
        const float mv  = __shfl(mk0, s);
        const float4 e = *(const float4*)(ebase + (size_t)ids * DD);
        acc.x = fmaf(e.x, mv, acc.x);
        acc.y = fmaf(e.y, mv, acc.y);
        acc.z = fmaf(e.z, mv, acc.z);
        acc.w = fmaf(e.w, mv, acc.w);
    }
    const float inv = 1.0f / fmaxf(msum, 1e-9f);
    float4 q = {acc.x * inv, acc.y * inv, acc.z * inv, acc.w * inv};
    // per-head norm: head = lane>>4 (16 lanes x 4 dims = 64 dims)
    float ss = q.x*q.x + q.y*q.y + q.z*q.z + q.w*q.w;
    ss += __shfl_xor(ss, 1); ss += __shfl_xor(ss, 2);
    ss += __shfl_xor(ss, 4); ss += __shfl_xor(ss, 8);
    const float rn = 1.0f / fmaxf(sqrtf(ss), 1e-6f);
    float4 xn = {q.x * rn, q.y * rn, q.z * rn, q.w * rn};
    *(float4*)(xq + (size_t)b * DD + lane * 4) = xn;
}

// -------- kernel 2 (MFMA): SLAY features. Blocks < NZBLK: sum phi_W into
// Zvec (norm folded in as row scale). Blocks >= NZBLK: write phiq for the
// (pre-normalized) queries. Wave = head; 16-row tiles; next tile prefetched.
__global__ __launch_bounds__(256) void k_phi(
    const float* __restrict__ W, const float* __restrict__ xq,
    const float* __restrict__ omega,
    float* __restrict__ Zvec, float* __restrict__ phiq,
    float s0f, float s1f, float q0f, float q1f, float cw0, float cw1)
{
    const int t = threadIdx.x;
    const int h = t >> 6, lane = t & 63, l15 = lane & 15, kg = lane >> 4;
    const bool isQ = blockIdx.x >= NZBLK;
    const float* base = isQ ? xq : W;
    const int l0 = (isQ ? (blockIdx.x - NZBLK) : blockIdx.x) * 256;

    // B fragments (omega, resident): col n = nt*16+l15, k = kh*32 + kg*8 + e
    short8 bf[4][2];
#pragma unroll
    for (int nt = 0; nt < 4; ++nt) {
        const int r = nt >> 1;
        const int m = (nt & 1) * 16 + l15;
        const float* ob = omega + (size_t)((r * NH + h) * DH) * MM + m;
#pragma unroll
        for (int kh = 0; kh < 2; ++kh)
#pragma unroll
            for (int e = 0; e < 8; ++e)
                bf[nt][kh][e] = f2bf(ob[(size_t)(kh * 32 + kg * 8 + e) * MM]);
    }

    float zp[4] = {0.f, 0.f, 0.f, 0.f};
    const float* sp = base + (size_t)(l0 + l15) * DD + h * DH + kg * 8;
    float4 c0 = *(const float4*)(sp);
    float4 c1 = *(const float4*)(sp + 4);
    float4 c2 = *(const float4*)(sp + 32);
    float4 c3 = *(const float4*)(sp + 36);

    for (int tl = 0; tl < 16; ++tl) {
        const float* np = sp + 16 * DD;
        float4 n0 = c0, n1 = c1, n2 = c2, n3 = c3;
        if (tl < 15) {                      // prefetch next tile
            n0 = *(const float4*)(np);
            n1 = *(const float4*)(np + 4);
            n2 = *(const float4*)(np + 32);
            n3 = *(const float4*)(np + 36);
        }

        float rnr[4];
        if (isQ) {
            rnr[0] = rnr[1] = rnr[2] = rnr[3] = 1.0f;  // pre-normalized
        } else {
            float ss = c0.x*c0.x + c0.y*c0.y + c0.z*c0.z + c0.w*c0.w
                     + c1.x*c1.x + c1.y*c1.y + c1.z*c1.z + c1.w*c1.w
                     + c2.x*c2.x + c2.y*c2.y + c2.z*c2.z + c2.w*c2.w
                     + c3.x*c3.x + c3.y*c3.y + c3.z*c3.z + c3.w*c3.w;
            ss += __shfl_xor(ss, 16);
            ss += __shfl_xor(ss, 32);
            float rn = 1.0f / fmaxf(sqrtf(ss), 1e-6f);
#pragma unroll
            for (int rr = 0; rr < 4; ++rr) rnr[rr] = __shfl(rn, kg * 4 + rr);
        }

        short8 a0, a1;
        a0[0]=f2bf(c0.x); a0[1]=f2bf(c0.y); a0[2]=f2bf(c0.z); a0[3]=f2bf(c0.w);
        a0[4]=f2bf(c1.x); a0[5]=f2bf(c1.y); a0[6]=f2bf(c1.z); a0[7]=f2bf(c1.w);
        a1[0]=f2bf(c2.x); a1[1]=f2bf(c2.y); a1[2]=f2bf(c2.z); a1[3]=f2bf(c2.w);
        a1[4]=f2bf(c3.x); a1[5]=f2bf(c3.y); a1[6]=f2bf(c3.z); a1[7]=f2bf(c3.w);

        f32x4 acc[4];
#pragma unroll
        for (int nt = 0; nt < 4; ++nt) {
            f32x4 c = {0.f, 0.f, 0.f, 0.f};
            c = __builtin_amdgcn_mfma_f32_16x16x32_bf16(a0, bf[nt][0], c, 0, 0, 0);
            c = __builtin_amdgcn_mfma_f32_16x16x32_bf16(a1, bf[nt][1], c, 0, 0, 0);
            acc[nt] = c;
        }

#pragma unroll
        for (int nt = 0; nt < 4; ++nt) {
            const float qv = (nt >> 1) ? q1f : q0f;
            const float sv = (nt >> 1) ? s1f : s0f;
            const float cw = (nt >> 1) ? cw1 : cw0;
            float zs = 0.0f;
#pragma unroll
            for (int rr = 0; rr < 4; ++rr) {
                float p   = acc[nt][rr] * rnr[rr];
                float arg = fminf(fmaxf(fmaf(p, qv, -sv), -10.0f), 10.0f);
                float phi = p * p * __expf(arg) * cw;
                if (isQ)
                    phiq[(size_t)(l0 + tl * 16 + kg * 4 + rr) * DD
                         + h * 64 + nt * 16 + l15] = phi;
                else
                    zs += phi;
            }
            zp[nt] += zs;
        }
        sp = np; c0 = n0; c1 = n1; c2 = n2; c3 = n3;
    }

    if (!isQ) {
#pragma unroll
        for (int nt = 0; nt < 4; ++nt) {
            float z = zp[nt];
            z += __shfl_xor(z, 16);
            z += __shfl_xor(z, 32);
            if (lane < 16) atomicAdd(&Zvec[h * 64 + nt * 16 + lane], z);
        }
    }
}

// -------- kernel 3: log_Z[b] = log(phiq[b] . Zvec + 1e-6); zero d_out
__global__ __launch_bounds__(256) void k_logz(
    const float* __restrict__ phiq, const float* __restrict__ Zvec,
    float* __restrict__ logZ, float* __restrict__ out)
{
    const int t = threadIdx.x, w = t >> 6, lane = t & 63;
    if (blockIdx.x == 0 && t == 0) out[0] = 0.0f;
    const int row = blockIdx.x * 4 + w;
    const float4* p4 = (const float4*)(phiq + (size_t)row * DD);
    const float4* z4 = (const float4*)Zvec;
    float4 a = p4[lane], z = z4[lane];
    float dot = a.x * z.x + a.y * z.y + a.z * z.z + a.w * z.w;
#pragma unroll
    for (int off = 32; off >= 1; off >>= 1) dot += __shfl_xor(dot, off);
    if (lane == 0) logZ[row] = logf(dot + 1e-6f);
}

// -------- kernel 4 (MFMA): ragged positive-label loss, 16 labels per block
__global__ __launch_bounds__(256) void k_loss(
    const int* __restrict__ flab, const int* __restrict__ sids,
    const float* __restrict__ W, const float* __restrict__ omega,
    const float* __restrict__ phiq, const float* __restrict__ logZ,
    float* __restrict__ out,
    float s0f, float s1f, float q0f, float q1f, float cw0, float cw1)
{
    const int t = threadIdx.x;
    const int h = t >> 6, lane = t & 63, l15 = lane & 15, kg = lane >> 4;
    const int i0 = blockIdx.x * 16;

    short8 bf[4][2];
#pragma unroll
    for (int nt = 0; nt < 4; ++nt) {
        const int r = nt >> 1;
        const int m = (nt & 1) * 16 + l15;
        const float* ob = omega + (size_t)((r * NH + h) * DH) * MM + m;
#pragma unroll
        for (int kh = 0; kh < 2; ++kh)
#pragma unroll
            for (int e = 0; e < 8; ++e)
                bf[nt][kh][e] = f2bf(ob[(size_t)(kh * 32 + kg * 8 + e) * MM]);
    }

    const int lab = flab[i0 + l15];
    const int sid = sids[i0 + l15];
    const float* wp = W + (size_t)lab * DD + h * DH + kg * 8;
    float4 c0 = *(const float4*)(wp);
    float4 c1 = *(const float4*)(wp + 4);
    float4 c2 = *(const float4*)(wp + 32);
    float4 c3 = *(const float4*)(wp + 36);

    float ss = c0.x*c0.x + c0.y*c0.y + c0.z*c0.z + c0.w*c0.w
             + c1.x*c1.x + c1.y*c1.y + c1.z*c1.z + c1.w*c1.w
             + c2.x*c2.x + c2.y*c2.y + c2.z*c2.z + c2.w*c2.w
             + c3.x*c3.x + c3.y*c3.y + c3.z*c3.z + c3.w*c3.w;
    ss += __shfl_xor(ss, 16);
    ss += __shfl_xor(ss, 32);
    float rn = 1.0f / fmaxf(sqrtf(ss), 1e-6f);
    float rnr[4];
    int   sidr[4];
#pragma unroll
    for (int rr = 0; rr < 4; ++rr) {
        rnr[rr]  = __shfl(rn,  kg * 4 + rr);
        sidr[rr] = __shfl(sid, kg * 4 + rr);
    }

    short8 a0, a1;
    a0[0]=f2bf(c0.x); a0[1]=f2bf(c0.y); a0[2]=f2bf(c0.z); a0[3]=f2bf(c0.w);
    a0[4]=f2bf(c1.x); a0[5]=f2bf(c1.y); a0[6]=f2bf(c1.z); a0[7]=f2bf(c1.w);
    a1[0]=f2bf(c2.x); a1[1]=f2bf(c2.y); a1[2]=f2bf(c2.z); a1[3]=f2bf(c2.w);
    a1[4]=f2bf(c3.x); a1[5]=f2bf(c3.y); a1[6]=f2bf(c3.z); a1[7]=f2bf(c3.w);

    f32x4 acc[4];
#pragma unroll
    for (int nt = 0; nt < 4; ++nt) {
        f32x4 c = {0.f, 0.f, 0.f, 0.f};
        c = __builtin_amdgcn_mfma_f32_16x16x32_bf16(a0, bf[nt][0], c, 0, 0, 0);
        c = __builtin_amdgcn_mfma_f32_16x16x32_bf16(a1, bf[nt][1], c, 0, 0, 0);
        acc[nt] = c;
    }

    float part[4] = {0.f, 0.f, 0.f, 0.f};
#pragma unroll
    for (int nt = 0; nt < 4; ++nt) {
        const float qv = (nt >> 1) ? q1f : q0f;
        const float sv = (nt >> 1) ? s1f : s0f;
        const float cw = (nt >> 1) ? cw1 : cw0;
#pragma unroll
        for (int rr = 0; rr < 4; ++rr) {
            float p   = acc[nt][rr] * rnr[rr];
            float arg = fminf(fmaxf(fmaf(p, qv, -sv), -10.0f), 10.0f);
            float phi = p * p * __expf(arg) * cw;
            part[rr] = fmaf(phi,
                            phiq[(size_t)sidr[rr] * DD + h * 64 + nt * 16 + l15],
                            part[rr]);
        }
    }
#pragma unroll
    for (int rr = 0; rr < 4; ++rr) {
        part[rr] += __shfl_xor(part[rr], 1);
        part[rr] += __shfl_xor(part[rr], 2);
        part[rr] += __shfl_xor(part[rr], 4);
        part[rr] += __shfl_xor(part[rr], 8);
    }
    __shared__ float lsum[NH][16];
    if (l15 == 0) {
#pragma unroll
        for (int rr = 0; rr < 4; ++rr) lsum[h][kg * 4 + rr] = part[rr];
    }
    __syncthreads();
    if (t < 16) {
        float num = lsum[0][t] + lsum[1][t] + lsum[2][t] + lsum[3][t] + 1e-6f;
        float term = logZ[sids[i0 + t]] - logf(num);
        term += __shfl_xor(term, 1);
        term += __shfl_xor(term, 2);
        term += __shfl_xor(term, 4);
        term += __shfl_xor(term, 8);
        if (t == 0) atomicAdd(out, term * (1.0f / (float)BB));
    }
}

extern "C" void kernel_launch(void* const* d_in, const int* in_sizes, int n_in,
                              void* d_out, int out_size, void* d_ws, size_t ws_size,
                              hipStream_t stream) {
    const int*   indices = (const int*)  d_in[0];
    const float* mask    = (const float*)d_in[1];
    const int*   flab    = (const int*)  d_in[2];
    const int*   sids    = (const int*)  d_in[3];
    const float* emb     = (const float*)d_in[4];
    const float* W       = (const float*)d_in[5];
    const float* omega   = (const float*)d_in[6];
    float* out = (float*)d_out;

    float* ws   = (float*)d_ws;
    float* phiq = ws;                   // BB*DD
    float* Zvec = phiq + BB * DD;       // DD
    float* logZ = Zvec + DD;            // BB
    float* xq   = logZ + BB;            // BB*DD (normalized queries)

    // Gauss-Laguerre R=2 constants (double precision on host)
    const double C  = 2.0 + 1e-6;
    const double s2 = sqrt(2.0);
    const double n0 = (2.0 - s2) / C, n1 = (2.0 + s2) / C;
    const double wt0 = ((2.0 + s2) / 4.0) / C, wt1 = ((2.0 - s2) / 4.0) / C;
    const float s0f = (float)n0,        s1f = (float)n1;
    const float q0f = (float)sqrt(2.0 * n0), q1f = (float)sqrt(2.0 * n1);
    const float cw0 = (float)(ISM * ISM * sqrt(wt0));
    const float cw1 = (float)(ISM * ISM * sqrt(wt1));

    k_gather<<<BB / 4, 256, 0, stream>>>(indices, mask, emb, xq, Zvec);
    k_phi<<<NZBLK + NQBLK, 256, 0, stream>>>(W, xq, omega, Zvec, phiq,
                                             s0f, s1f, q0f, q1f, cw0, cw1);
    k_logz<<<BB / 4, 256, 0, stream>>>(phiq, Zvec, logZ, out);
    k_loss<<<TLAB / 16, 256, 0, stream>>>(flab, sids, W, omega, phiq, logZ,
                                          out, s0f, s1f, q0f, q1f, cw0, cw1);
}